// Round 2
// baseline (477.124 us; speedup 1.0000x reference)
//
#include <hip/hip_runtime.h>
#include <hip/hip_bf16.h>

#define DIM 384
#define SEQ 3136   // 56*56
#define NBATCH 8

typedef __attribute__((ext_vector_type(8))) short short8;  // 8 x bf16 (4 VGPRs)
typedef __attribute__((ext_vector_type(4))) float fx4;
typedef __attribute__((ext_vector_type(4))) int i4;
typedef __hip_bfloat16 bf16;

#define MFMA(a,b,c) __builtin_amdgcn_mfma_f32_16x16x32_bf16(a,b,c,0,0,0)

// -------- x[b][c][n] f32 -> kb[b][n][c] bf16 (transpose + convert) --------
__global__ __launch_bounds__(256) void ktrans(const float* __restrict__ x,
                                              bf16* __restrict__ kb) {
  __shared__ float t[64][65];
  int b = blockIdx.z;
  int n0 = blockIdx.x * 64, c0 = blockIdx.y * 64;
  int tid = threadIdx.x;
  {
    int nl = tid & 63, cl = tid >> 6;
    const float* xp = x + ((size_t)b * DIM + c0) * SEQ + n0;
    #pragma unroll
    for (int p = 0; p < 16; ++p) {
      int c = cl * 16 + p;
      t[c][nl] = xp[(size_t)c * SEQ + nl];
    }
  }
  __syncthreads();
  {
    int cc = tid & 63, nr = tid >> 6;
    bf16* kp = kb + ((size_t)b * SEQ + n0) * DIM + c0;
    #pragma unroll
    for (int p = 0; p < 16; ++p) {
      int n = nr * 16 + p;
      kp[(size_t)n * DIM + cc] = __float2bfloat16(t[cc][n]);
    }
  }
}

// -------- weights f32 -> bf16 --------
__global__ __launch_bounds__(256) void kwconv(const float* __restrict__ w1,
                                              const float* __restrict__ w2,
                                              bf16* __restrict__ w1b,
                                              bf16* __restrict__ w2b) {
  int i = blockIdx.x * 256 + threadIdx.x;   // grid covers DIM*DIM exactly
  w1b[i] = __float2bfloat16(w1[i]);
  w2b[i] = __float2bfloat16(w2[i]);
}

// -------- out[r][c] = sum_k A[r][k] * Bt[c][k]   (both K-contiguous, K=384) --------
__global__ __launch_bounds__(256, 1) void kgemm(const bf16* __restrict__ A, long long Abs,
                                                const bf16* __restrict__ Bt, long long Bbs,
                                                bf16* __restrict__ out, long long Obs, int ldo) {
  __shared__ __align__(16) bf16 At[64][DIM + 8];
  __shared__ __align__(16) bf16 Bs[64][DIM + 8];
  int b = blockIdx.z;
  int tid = threadIdx.x;
  const bf16* Ab = A + (size_t)b * Abs + (size_t)blockIdx.x * 64 * DIM;
  const bf16* Bb = Bt + (size_t)b * Bbs + (size_t)blockIdx.y * 64 * DIM;
  {
    int row = tid >> 2, cb = (tid & 3) * 96;
    const i4* ga = (const i4*)(Ab + (size_t)row * DIM + cb);
    const i4* gb = (const i4*)(Bb + (size_t)row * DIM + cb);
    i4* la = (i4*)(&At[row][cb]);
    i4* lb = (i4*)(&Bs[row][cb]);
    #pragma unroll
    for (int p = 0; p < 12; ++p) { la[p] = ga[p]; lb[p] = gb[p]; }
  }
  __syncthreads();
  int wave = tid >> 6, lane = tid & 63;
  int r = lane & 15, kq = lane >> 4;
  fx4 zero = {0.f, 0.f, 0.f, 0.f};
  fx4 acc[4];
  #pragma unroll
  for (int i = 0; i < 4; ++i) acc[i] = zero;
  #pragma unroll
  for (int ks = 0; ks < 12; ++ks) {
    short8 af = *(const short8*)(&At[wave * 16 + r][ks * 32 + kq * 8]);
    #pragma unroll
    for (int ct = 0; ct < 4; ++ct) {
      short8 bfr = *(const short8*)(&Bs[ct * 16 + r][ks * 32 + kq * 8]);
      acc[ct] = MFMA(af, bfr, acc[ct]);
    }
  }
  bf16* ob = out + (size_t)b * Obs
           + (size_t)(blockIdx.x * 64 + wave * 16 + kq * 4) * ldo + blockIdx.y * 64;
  #pragma unroll
  for (int ct = 0; ct < 4; ++ct)
    #pragma unroll
    for (int rr = 0; rr < 4; ++rr)
      ob[(size_t)rr * ldo + ct * 16 + r] = __float2bfloat16(acc[ct][rr]);
}

// -------- fused attention: S = Q*K^T (no-max softmax), O = P*V / rowsum --------
// grid (8, 98): blockIdx.x = batch (-> XCD via %8), blockIdx.y = 32-row n-tile.
// 512 threads / 8 waves. Round-0 inner-loop structure (m-tile 64, 2 barriers,
// K staged in LDS, V direct global gathers) but re-decomposed for occupancy:
//   QK: wave w owns S rows rg=w>>2 (16 of 32), m-cols ch=w&3 (16 of 64) -> 12 MFMA
//   PV: wave w owns d-cols [w*48, +48)                                  -> 12 MFMA
// Per-wave regs: qf 48 + acc 24 -> fits 128 VGPR => 4 waves/SIMD with 2 blocks/CU
// (LDS 55KB). 784 blocks: balanced residency; occupancy ~4 waves/SIMD vs 1.5 before.
__global__ __launch_bounds__(512, 4) void kattn(const bf16* __restrict__ Qb,
                                                const bf16* __restrict__ Kb,
                                                const bf16* __restrict__ Vt,
                                                float* __restrict__ out) {
  __shared__ __align__(16) bf16 Kl[64][DIM + 8];   // 50,176 B
  __shared__ __align__(16) bf16 Pl[2][16][68];     //  4,352 B
  __shared__ float rsum2[4][32];                   //    512 B

  int b = blockIdx.x;
  int n0 = blockIdx.y * 32;
  int tid = threadIdx.x;
  int wave = tid >> 6, lane = tid & 63;
  int r = lane & 15, kq = lane >> 4;
  int rg = wave >> 2;   // which 16-row half of the 32 Q rows (QK)
  int ch = wave & 3;    // which 16-col quarter of the 64 m-cols (QK)

  // Q fragments for this wave's 16 rows, full K=384 (12 k-steps)
  short8 qf[12];
  {
    const bf16* qp = Qb + ((size_t)b * SEQ + n0 + rg * 16 + r) * DIM + kq * 8;
    #pragma unroll
    for (int ks = 0; ks < 12; ++ks) qf[ks] = *(const short8*)(qp + ks * 32);
  }
  fx4 zero = {0.f, 0.f, 0.f, 0.f};
  fx4 acc[2][3];
  #pragma unroll
  for (int i = 0; i < 2; ++i)
    #pragma unroll
    for (int j = 0; j < 3; ++j) acc[i][j] = zero;
  float rs[4] = {0.f, 0.f, 0.f, 0.f};
  const float cexp = 0.07362223f;   // log2(e)/sqrt(384): exp(s*scale) = exp2(s*cexp)

  const bf16* kbase = Kb + (size_t)b * SEQ * DIM;
  const bf16* vbase = Vt + (size_t)b * DIM * SEQ;

  // K staging geometry (512 threads, 64 rows x 384 cols): 6 x i4 per thread
  int krow = tid >> 3, kcs = (tid & 7) * 48;

  for (int im = 0; im < SEQ / 64; ++im) {
    int m0 = im * 64;
    { // stage K tile: 64 rows x 384 bf16
      const i4* g = (const i4*)(kbase + (size_t)(m0 + krow) * DIM + kcs);
      i4* l = (i4*)(&Kl[krow][kcs]);
      #pragma unroll
      for (int p = 0; p < 6; ++p) l[p] = g[p];
    }
    // V fragments direct from global (L2): latency hides under QK
    short8 vf[2][3];
    #pragma unroll
    for (int ks2 = 0; ks2 < 2; ++ks2)
      #pragma unroll
      for (int dtl = 0; dtl < 3; ++dtl) {
        int d = wave * 48 + dtl * 16 + r;
        vf[ks2][dtl] = *(const short8*)(vbase + (size_t)d * SEQ + m0 + ks2 * 32 + kq * 8);
      }
    __syncthreads();   // A: Kl ready; also all waves done PV(im-1) -> Pl free
    // S = Q * K^T : this wave's 16 rows x 16 cols
    fx4 sa = zero;
    #pragma unroll
    for (int ks = 0; ks < 12; ++ks) {
      short8 bfr = *(const short8*)(&Kl[ch * 16 + r][ks * 32 + kq * 8]);
      sa = MFMA(qf[ks], bfr, sa);
    }
    // exp (no max subtraction), partial per-lane rowsum, P -> LDS
    #pragma unroll
    for (int rr = 0; rr < 4; ++rr) {
      float e0 = exp2f(sa[rr] * cexp);
      Pl[rg][kq * 4 + rr][ch * 16 + r] = __float2bfloat16(e0);
      rs[rr] += e0;
    }
    __syncthreads();   // B: Pl ready; also all waves done QK -> Kl free next iter
    // PV: O[g2*16+i][d] += P[g2*16+i][m] * V[m][d], wave's 48 d-cols
    #pragma unroll
    for (int ks2 = 0; ks2 < 2; ++ks2) {
      short8 pa[2];
      #pragma unroll
      for (int g2 = 0; g2 < 2; ++g2)
        pa[g2] = *(const short8*)(&Pl[g2][r][ks2 * 32 + kq * 8]);
      #pragma unroll
      for (int dtl = 0; dtl < 3; ++dtl) {
        #pragma unroll
        for (int g2 = 0; g2 < 2; ++g2)
          acc[g2][dtl] = MFMA(pa[g2], vf[ks2][dtl], acc[g2][dtl]);
      }
    }
  }
  // rowsum: per-wave partial covers its 16 m-cols; reduce over the 16 r-lanes,
  // then sum the 4 ch-waves' contributions in the epilogue.
  #pragma unroll
  for (int rr = 0; rr < 4; ++rr) {
    float v = rs[rr];
    v += __shfl_xor(v, 1);
    v += __shfl_xor(v, 2);
    v += __shfl_xor(v, 4);
    v += __shfl_xor(v, 8);
    if (r == 0) rsum2[ch][rg * 16 + kq * 4 + rr] = v;
  }
  __syncthreads();
  // epilogue: divide and store transposed: out[b][d][n]
  float* ob = out + (size_t)b * DIM * SEQ;
  #pragma unroll
  for (int g2 = 0; g2 < 2; ++g2) {
    #pragma unroll
    for (int rr = 0; rr < 4; ++rr) {
      int row = g2 * 16 + kq * 4 + rr;
      float inv = 1.0f / (rsum2[0][row] + rsum2[1][row] + rsum2[2][row] + rsum2[3][row]);
      int n = n0 + row;
      #pragma unroll
      for (int dtl = 0; dtl < 3; ++dtl) {
        int d = wave * 48 + dtl * 16 + r;
        ob[(size_t)d * SEQ + n] = acc[g2][dtl][rr] * inv;
      }
    }
  }
}

extern "C" void kernel_launch(void* const* d_in, const int* in_sizes, int n_in,
                              void* d_out, int out_size, void* d_ws, size_t ws_size,
                              hipStream_t stream) {
  const float* x  = (const float*)d_in[0];
  const float* w1 = (const float*)d_in[1];
  const float* w2 = (const float*)d_in[2];
  float* out = (float*)d_out;

  char* ws = (char*)d_ws;
  size_t SZ = (size_t)NBATCH * SEQ * DIM * sizeof(bf16);   // 19,267,584 B
  bf16* Kb  = (bf16*)(ws);                 // [B][N][C]
  bf16* Qb  = (bf16*)(ws + SZ);            // [B][N][C]
  bf16* Vt  = (bf16*)(ws + 2 * SZ);        // [B][C][N]
  bf16* w1b = (bf16*)(ws + 3 * SZ);
  bf16* w2b = (bf16*)(ws + 3 * SZ + (size_t)DIM * DIM * sizeof(bf16));

  // 1) transpose+convert x -> Kb
  ktrans<<<dim3(SEQ / 64, DIM / 64, NBATCH), 256, 0, stream>>>(x, Kb);
  // 2) weights -> bf16
  kwconv<<<dim3(DIM * DIM / 256), 256, 0, stream>>>(w1, w2, w1b, w2b);
  // 3) Q[b][n][d] = sum_c Kb[b][n][c] * w1[d][c]
  kgemm<<<dim3(SEQ / 64, DIM / 64, NBATCH), 256, 0, stream>>>(
      Kb, (long long)SEQ * DIM, w1b, 0LL, Qb, (long long)SEQ * DIM, DIM);
  // 4) Vt[b][d][m] = sum_c w2[d][c] * Kb[b][m][c]
  kgemm<<<dim3(DIM / 64, SEQ / 64, NBATCH), 256, 0, stream>>>(
      w2b, 0LL, Kb, (long long)SEQ * DIM, Vt, (long long)DIM * SEQ, SEQ);
  // 5) fused attention -> out[b][d][n]  (batch on blockIdx.x -> one XCD per batch)
  kattn<<<dim3(NBATCH, SEQ / 32), 512, 0, stream>>>(Qb, Kb, Vt, out);
}

// Round 3
// 463.363 us; speedup vs baseline: 1.0297x; 1.0297x over previous
//
#include <hip/hip_runtime.h>
#include <hip/hip_bf16.h>

#define DIM 384
#define SEQ 3136   // 56*56
#define NBATCH 8

typedef __attribute__((ext_vector_type(8))) short short8;  // 8 x bf16 (4 VGPRs)
typedef __attribute__((ext_vector_type(4))) float fx4;
typedef __attribute__((ext_vector_type(4))) int i4;
typedef __hip_bfloat16 bf16;

#define MFMA(a,b,c) __builtin_amdgcn_mfma_f32_16x16x32_bf16(a,b,c,0,0,0)

// -------- x[b][c][n] f32 -> kb[b][n][c] bf16 (transpose + convert) --------
__global__ __launch_bounds__(256) void ktrans(const float* __restrict__ x,
                                              bf16* __restrict__ kb) {
  __shared__ float t[64][65];
  int b = blockIdx.z;
  int n0 = blockIdx.x * 64, c0 = blockIdx.y * 64;
  int tid = threadIdx.x;
  {
    int nl = tid & 63, cl = tid >> 6;
    const float* xp = x + ((size_t)b * DIM + c0) * SEQ + n0;
    #pragma unroll
    for (int p = 0; p < 16; ++p) {
      int c = cl * 16 + p;
      t[c][nl] = xp[(size_t)c * SEQ + nl];
    }
  }
  __syncthreads();
  {
    int cc = tid & 63, nr = tid >> 6;
    bf16* kp = kb + ((size_t)b * SEQ + n0) * DIM + c0;
    #pragma unroll
    for (int p = 0; p < 16; ++p) {
      int n = nr * 16 + p;
      kp[(size_t)n * DIM + cc] = __float2bfloat16(t[cc][n]);
    }
  }
}

// -------- weights f32 -> bf16 --------
__global__ __launch_bounds__(256) void kwconv(const float* __restrict__ w1,
                                              const float* __restrict__ w2,
                                              bf16* __restrict__ w1b,
                                              bf16* __restrict__ w2b) {
  int i = blockIdx.x * 256 + threadIdx.x;   // grid covers DIM*DIM exactly
  w1b[i] = __float2bfloat16(w1[i]);
  w2b[i] = __float2bfloat16(w2[i]);
}

// -------- out[r][c] = sum_k A[r][k] * Bt[c][k]   (both K-contiguous, K=384) --------
__global__ __launch_bounds__(256, 1) void kgemm(const bf16* __restrict__ A, long long Abs,
                                                const bf16* __restrict__ Bt, long long Bbs,
                                                bf16* __restrict__ out, long long Obs, int ldo) {
  __shared__ __align__(16) bf16 At[64][DIM + 8];
  __shared__ __align__(16) bf16 Bs[64][DIM + 8];
  int b = blockIdx.z;
  int tid = threadIdx.x;
  const bf16* Ab = A + (size_t)b * Abs + (size_t)blockIdx.x * 64 * DIM;
  const bf16* Bb = Bt + (size_t)b * Bbs + (size_t)blockIdx.y * 64 * DIM;
  {
    int row = tid >> 2, cb = (tid & 3) * 96;
    const i4* ga = (const i4*)(Ab + (size_t)row * DIM + cb);
    const i4* gb = (const i4*)(Bb + (size_t)row * DIM + cb);
    i4* la = (i4*)(&At[row][cb]);
    i4* lb = (i4*)(&Bs[row][cb]);
    #pragma unroll
    for (int p = 0; p < 12; ++p) { la[p] = ga[p]; lb[p] = gb[p]; }
  }
  __syncthreads();
  int wave = tid >> 6, lane = tid & 63;
  int r = lane & 15, kq = lane >> 4;
  fx4 zero = {0.f, 0.f, 0.f, 0.f};
  fx4 acc[4];
  #pragma unroll
  for (int i = 0; i < 4; ++i) acc[i] = zero;
  #pragma unroll
  for (int ks = 0; ks < 12; ++ks) {
    short8 af = *(const short8*)(&At[wave * 16 + r][ks * 32 + kq * 8]);
    #pragma unroll
    for (int ct = 0; ct < 4; ++ct) {
      short8 bfr = *(const short8*)(&Bs[ct * 16 + r][ks * 32 + kq * 8]);
      acc[ct] = MFMA(af, bfr, acc[ct]);
    }
  }
  bf16* ob = out + (size_t)b * Obs
           + (size_t)(blockIdx.x * 64 + wave * 16 + kq * 4) * ldo + blockIdx.y * 64;
  #pragma unroll
  for (int ct = 0; ct < 4; ++ct)
    #pragma unroll
    for (int rr = 0; rr < 4; ++rr)
      ob[(size_t)rr * ldo + ct * 16 + r] = __float2bfloat16(acc[ct][rr]);
}

// -------- fused attention: S = Q*K^T (no-max softmax), O = P*V / rowsum --------
// Round-0 structure (grid (8,49), 4 waves, m-tile 64, 2 barriers/iter, K in LDS,
// V direct global gathers) with ONE change: QK decomposition is now 32 rows x
// 32 cols per wave (2 A-frags x 2 B-frags per k-step) instead of 16 x 64.
// Each K-fragment ds_read_b128 feeds 2 MFMAs -> QK LDS reads halve (192->96
// per iter). MFMA count unchanged. qf doubles to 96 VGPR -- free, because LDS
// (59392 B -> 2 blocks/CU = 2 waves/SIMD) permits 256 VGPR/wave anyway.
__global__ __launch_bounds__(256, 2) void kattn(const bf16* __restrict__ Qb,
                                                const bf16* __restrict__ Kb,
                                                const bf16* __restrict__ Vt,
                                                float* __restrict__ out) {
  __shared__ __align__(16) bf16 Kl[64][DIM + 8];   // 50,176 B
  __shared__ __align__(16) bf16 Pl[64][68];        //  8,704 B (row stride 34 dw)
  __shared__ float rsum2[2][64];                   //    512 B

  int b = blockIdx.x;
  int n0 = blockIdx.y * 64;
  int tid = threadIdx.x;
  int wave = tid >> 6, lane = tid & 63;
  int r = lane & 15, kq = lane >> 4;
  int rh = wave >> 1;    // row-half of the 64 n-rows (32 rows)
  int chh = wave & 1;    // col-half of the 64 m-cols (32 cols)

  // Q fragments: this wave's 32 rows (2 x 16), full K=384 (12 k-steps). 96 VGPR.
  short8 qf[2][12];
  #pragma unroll
  for (int ri = 0; ri < 2; ++ri) {
    const bf16* qp = Qb + ((size_t)b * SEQ + n0 + rh * 32 + ri * 16 + r) * DIM + kq * 8;
    #pragma unroll
    for (int ks = 0; ks < 12; ++ks) qf[ri][ks] = *(const short8*)(qp + ks * 32);
  }
  fx4 zero = {0.f, 0.f, 0.f, 0.f};
  fx4 acc[4][6];
  #pragma unroll
  for (int i = 0; i < 4; ++i)
    #pragma unroll
    for (int j = 0; j < 6; ++j) acc[i][j] = zero;
  float rs[2][4] = {{0.f, 0.f, 0.f, 0.f}, {0.f, 0.f, 0.f, 0.f}};
  const float cexp = 0.07362223f;   // log2(e)/sqrt(384): exp(s*scale) = exp2(s*cexp)

  const bf16* kbase = Kb + (size_t)b * SEQ * DIM;
  const bf16* vbase = Vt + (size_t)b * DIM * SEQ;

  // staging geometry (per thread): one K row quarter
  int srow = tid >> 2, scb = (tid & 3) * 96;

  for (int im = 0; im < SEQ / 64; ++im) {
    int m0 = im * 64;
    { // stage K tile: 64 rows x 384 bf16 (reg-staged in two 6-deep halves)
      const i4* g = (const i4*)(kbase + (size_t)(m0 + srow) * DIM + scb);
      i4* l = (i4*)(&Kl[srow][scb]);
      i4 t0[6];
      #pragma unroll
      for (int p = 0; p < 6; ++p) t0[p] = g[p];
      #pragma unroll
      for (int p = 0; p < 6; ++p) l[p] = t0[p];
      #pragma unroll
      for (int p = 0; p < 6; ++p) t0[p] = g[6 + p];
      #pragma unroll
      for (int p = 0; p < 6; ++p) l[6 + p] = t0[p];
    }
    // V fragments direct from global (L2): 16-line packed loads, hide under QK
    short8 vf[2][6];
    #pragma unroll
    for (int ks2 = 0; ks2 < 2; ++ks2)
      #pragma unroll
      for (int dtl = 0; dtl < 6; ++dtl) {
        int d = (wave * 6 + dtl) * 16 + r;
        vf[ks2][dtl] = *(const short8*)(vbase + (size_t)d * SEQ + m0 + ks2 * 32 + kq * 8);
      }
    __syncthreads();   // A: Kl ready; also all waves done PV(im-1) -> Pl free
    // S = Q * K^T : this wave's 32 rows x 32 cols (2x2 of 16x16)
    fx4 sa[2][2] = {{zero, zero}, {zero, zero}};
    #pragma unroll
    for (int ks = 0; ks < 12; ++ks) {
      short8 b0 = *(const short8*)(&Kl[chh * 32 + r][ks * 32 + kq * 8]);
      short8 b1 = *(const short8*)(&Kl[chh * 32 + 16 + r][ks * 32 + kq * 8]);
      sa[0][0] = MFMA(qf[0][ks], b0, sa[0][0]);
      sa[0][1] = MFMA(qf[0][ks], b1, sa[0][1]);
      sa[1][0] = MFMA(qf[1][ks], b0, sa[1][0]);
      sa[1][1] = MFMA(qf[1][ks], b1, sa[1][1]);
    }
    // exp (no max subtraction), partial per-lane rowsum, P -> LDS
    #pragma unroll
    for (int ri = 0; ri < 2; ++ri)
      #pragma unroll
      for (int rr = 0; rr < 4; ++rr) {
        float e0 = exp2f(sa[ri][0][rr] * cexp);
        float e1 = exp2f(sa[ri][1][rr] * cexp);
        int row = rh * 32 + ri * 16 + kq * 4 + rr;
        Pl[row][chh * 32 + r]      = __float2bfloat16(e0);
        Pl[row][chh * 32 + 16 + r] = __float2bfloat16(e1);
        rs[ri][rr] += e0 + e1;
      }
    __syncthreads();   // B: Pl ready; also all waves done QK -> Kl free next iter
    // PV: O[rg*16+i][d] += P[rg*16+i][m] * V[m][d], wave's 96 d-cols
    #pragma unroll
    for (int ks2 = 0; ks2 < 2; ++ks2) {
      short8 pa[4];
      #pragma unroll
      for (int rg = 0; rg < 4; ++rg)
        pa[rg] = *(const short8*)(&Pl[rg * 16 + r][ks2 * 32 + kq * 8]);
      #pragma unroll
      for (int dtl = 0; dtl < 6; ++dtl) {
        #pragma unroll
        for (int rg = 0; rg < 4; ++rg)
          acc[rg][dtl] = MFMA(pa[rg], vf[ks2][dtl], acc[rg][dtl]);
      }
    }
  }
  // rowsum: reduce each wave's 32-col partial over the 16 r-lanes; the two
  // col-half waves sharing the same rows combine in the epilogue.
  #pragma unroll
  for (int ri = 0; ri < 2; ++ri)
    #pragma unroll
    for (int rr = 0; rr < 4; ++rr) {
      float v = rs[ri][rr];
      v += __shfl_xor(v, 1);
      v += __shfl_xor(v, 2);
      v += __shfl_xor(v, 4);
      v += __shfl_xor(v, 8);
      if (r == 0) rsum2[chh][rh * 32 + ri * 16 + kq * 4 + rr] = v;
    }
  __syncthreads();
  // epilogue: divide and store transposed: out[b][d][n]
  float* ob = out + (size_t)b * DIM * SEQ;
  #pragma unroll
  for (int rg = 0; rg < 4; ++rg) {
    #pragma unroll
    for (int rr = 0; rr < 4; ++rr) {
      int row = rg * 16 + kq * 4 + rr;
      float inv = 1.0f / (rsum2[0][row] + rsum2[1][row]);
      int n = n0 + row;
      #pragma unroll
      for (int dtl = 0; dtl < 6; ++dtl) {
        int d = (wave * 6 + dtl) * 16 + r;
        ob[(size_t)d * SEQ + n] = acc[rg][dtl][rr] * inv;
      }
    }
  }
}

extern "C" void kernel_launch(void* const* d_in, const int* in_sizes, int n_in,
                              void* d_out, int out_size, void* d_ws, size_t ws_size,
                              hipStream_t stream) {
  const float* x  = (const float*)d_in[0];
  const float* w1 = (const float*)d_in[1];
  const float* w2 = (const float*)d_in[2];
  float* out = (float*)d_out;

  char* ws = (char*)d_ws;
  size_t SZ = (size_t)NBATCH * SEQ * DIM * sizeof(bf16);   // 19,267,584 B
  bf16* Kb  = (bf16*)(ws);                 // [B][N][C]
  bf16* Qb  = (bf16*)(ws + SZ);            // [B][N][C]
  bf16* Vt  = (bf16*)(ws + 2 * SZ);        // [B][C][N]
  bf16* w1b = (bf16*)(ws + 3 * SZ);
  bf16* w2b = (bf16*)(ws + 3 * SZ + (size_t)DIM * DIM * sizeof(bf16));

  // 1) transpose+convert x -> Kb
  ktrans<<<dim3(SEQ / 64, DIM / 64, NBATCH), 256, 0, stream>>>(x, Kb);
  // 2) weights -> bf16
  kwconv<<<dim3(DIM * DIM / 256), 256, 0, stream>>>(w1, w2, w1b, w2b);
  // 3) Q[b][n][d] = sum_c Kb[b][n][c] * w1[d][c]
  kgemm<<<dim3(SEQ / 64, DIM / 64, NBATCH), 256, 0, stream>>>(
      Kb, (long long)SEQ * DIM, w1b, 0LL, Qb, (long long)SEQ * DIM, DIM);
  // 4) Vt[b][d][m] = sum_c w2[d][c] * Kb[b][m][c]
  kgemm<<<dim3(DIM / 64, SEQ / 64, NBATCH), 256, 0, stream>>>(
      w2b, 0LL, Kb, (long long)SEQ * DIM, Vt, (long long)DIM * SEQ, SEQ);
  // 5) fused attention -> out[b][d][n]  (batch on blockIdx.x -> one XCD per batch)
  kattn<<<dim3(NBATCH, SEQ / 64), 256, 0, stream>>>(Qb, Kb, Vt, out);
}